// Round 2
// baseline (117.285 us; speedup 1.0000x reference)
//
#include <hip/hip_runtime.h>

// 3x3 conv, stride 1, pad 1, 4096x4096 fp32.
// R9: latency-bound fix (R8 post-mortem: occupancy 20%, VALUBusy 7.6%,
// hbm 26% — grid of 512 blocks capped residency at 2 blocks/CU).
//   - STEPS 8 -> 2: 8-row stripes, grid = 2048 blocks = 8 blocks/CU of work.
//   - ALL 10 input rows (30 VMEM ops/thread) issued up-front: max MLP,
//     no software pipeline, no register rotation.
//   - __launch_bounds__(256, 5): VGPR cap 102 fits the ~90-reg live state
//     without spills; 20 waves/CU = 62.5% occupancy cap (vs 25% in R8).
//   - XCD banding kept (2048 % 8 == 0, bijective): vertically adjacent
//     stripes share halo rows in one XCD's L2.

#define H 4096
#define W 4096
#define CPT 4      // cols per thread
#define RPT 4      // rows per step
#define STEPS 2    // steps per block (stripe = 8 rows)
#define BLOCK 256
#define NROWS (STEPS * RPT + 2)   // 10 input rows per stripe
#define NBX (W / (BLOCK * CPT))   // 4 col-blocks
#define NBY (H / (STEPS * RPT))   // 512 row-stripes
#define XCDS 8
#define BANDY (NBY / XCDS)        // 64 stripes per XCD band

typedef float vfloat4 __attribute__((ext_vector_type(4)));

__device__ __forceinline__ void load_row(const float* __restrict__ x, int rr,
                                         int c, vfloat4& v, float& lf, float& rt) {
    if (rr >= 0 && rr < H) {
        const float* row = x + (size_t)rr * W + c;
        v = *(const vfloat4*)row;
        lf = (c > 0) ? row[-1] : 0.0f;
        rt = (c + CPT < W) ? row[CPT] : 0.0f;
    } else {
        v = (vfloat4)(0.f);
        lf = 0.f;
        rt = 0.f;
    }
}

__global__ __launch_bounds__(BLOCK, 5) void conv3x3_stripe(
    const float* __restrict__ x, const float* __restrict__ w9,
    const float* __restrict__ bias, float* __restrict__ out) {
    // XCD-banded bijective remap: linear id round-robins across 8 XCDs, so
    // id = slot*8 + xcd gives each XCD a contiguous band of 64 stripes.
    const int id = blockIdx.x;
    const int xcd = id & (XCDS - 1);
    const int slot = id >> 3;                 // 0..255
    const int bx = slot & (NBX - 1);          // 0..3
    const int byb = slot >> 2;                // 0..63
    const int by = xcd * BANDY + byb;         // 0..511

    const int c = (bx * BLOCK + threadIdx.x) * CPT;
    const int rbase = by * (STEPS * RPT);

    // Issue ALL input rows up front: 30 VMEM ops in flight per thread.
    vfloat4 v[NROWS];
    float lf[NROWS], rt[NROWS];
#pragma unroll
    for (int i = 0; i < NROWS; ++i)
        load_row(x, rbase - 1 + i, c, v[i], lf[i], rt[i]);

    float wv[9];
#pragma unroll
    for (int i = 0; i < 9; ++i) wv[i] = w9[i];
    const float b = bias[0];

#pragma unroll
    for (int s = 0; s < STEPS; ++s) {
        const int r0 = rbase + s * RPT;

        vfloat4 acc[RPT];
#pragma unroll
        for (int j = 0; j < RPT; ++j) acc[j] = (vfloat4)(b);

#pragma unroll
        for (int j = 0; j < RPT; ++j) {
#pragma unroll
            for (int dr = 0; dr < 3; ++dr) {
                const int i = s * RPT + j + dr;   // compile-time index, 0..9
                const float w0 = wv[dr * 3 + 0];
                const float w1 = wv[dr * 3 + 1];
                const float w2 = wv[dr * 3 + 2];
                acc[j].x = fmaf(w0, lf[i],  fmaf(w1, v[i].x, fmaf(w2, v[i].y, acc[j].x)));
                acc[j].y = fmaf(w0, v[i].x, fmaf(w1, v[i].y, fmaf(w2, v[i].z, acc[j].y)));
                acc[j].z = fmaf(w0, v[i].y, fmaf(w1, v[i].z, fmaf(w2, v[i].w, acc[j].z)));
                acc[j].w = fmaf(w0, v[i].z, fmaf(w1, v[i].w, fmaf(w2, rt[i],  acc[j].w)));
            }
        }

#pragma unroll
        for (int j = 0; j < RPT; ++j) {
            __builtin_nontemporal_store(acc[j],
                (vfloat4*)(out + (size_t)(r0 + j) * W + c));
        }
    }
}

extern "C" void kernel_launch(void* const* d_in, const int* in_sizes, int n_in,
                              void* d_out, int out_size, void* d_ws, size_t ws_size,
                              hipStream_t stream) {
    const float* x = (const float*)d_in[0];
    const float* w = (const float*)d_in[1];
    const float* bias = (const float*)d_in[2];
    float* out = (float*)d_out;

    dim3 block(BLOCK, 1, 1);
    dim3 grid(NBX * NBY, 1, 1);   // 2048 blocks, XCD-banded remap in-kernel
    conv3x3_stripe<<<grid, block, 0, stream>>>(x, w, bias, out);
}

// Round 3
// 112.839 us; speedup vs baseline: 1.0394x; 1.0394x over previous
//
#include <hip/hip_runtime.h>

// 3x3 conv, stride 1, pad 1, 4096x4096 fp32.
// R10: occupancy-first redesign (R9 post-mortem: duration scales ~inversely
// with resident waves -> latency-bound; need ~100% occupancy to reach BW).
//   - One 4-row step per block, 6 input rows in regs: v[6]=24 + acc[4]=16.
//   - Column halos via intra-wave shuffles (__shfl_up/__shfl_down) instead
//     of 20 scalar loads/thread; only lanes 0/63 patch from memory
//     (6 predicated dword loads into one 6-reg array).
//   - Weights/bias are uniform loads -> SGPR-promoted (no VGPR cost).
//   - Estimated live state ~58 VGPRs; __launch_bounds__(256, 8) targets
//     64-VGPR allocation = 8 waves/SIMD = 100% occupancy.
//   - Grid 4096 blocks (16/CU of work), XCD-banded (4096 % 8 == 0):
//     vertically adjacent 4-row stripes share halo rows in one XCD's L2,
//     absorbing the 1.5x vector read amplification.
//   - Accumulation order per output is bit-identical to R9 (rows j,j+1,j+2,
//     same fmaf chain) -> absmax unchanged.

#define H 4096
#define W 4096
#define CPT 4                    // cols per thread
#define RPT 4                    // output rows per block
#define BLOCK 256
#define NROWS (RPT + 2)          // 6 input rows
#define NBX (W / (BLOCK * CPT))  // 4 col-blocks
#define NBY (H / RPT)            // 1024 row-stripes
#define XCDS 8
#define BANDY (NBY / XCDS)       // 128 stripes per XCD band

typedef float vfloat4 __attribute__((ext_vector_type(4)));

__global__ __launch_bounds__(BLOCK, 8) void conv3x3_stripe(
    const float* __restrict__ x, const float* __restrict__ w9,
    const float* __restrict__ bias, float* __restrict__ out) {
    // XCD-banded bijective remap: linear id round-robins across 8 XCDs, so
    // id = slot*8 + xcd gives each XCD a contiguous band of 128 stripes;
    // within a band, bx varies fastest so vertically adjacent stripes are
    // temporally close on the same XCD's L2.
    const int id = blockIdx.x;
    const int xcd = id & (XCDS - 1);
    const int slot = id >> 3;                 // 0..511
    const int bx = slot & (NBX - 1);          // 0..3
    const int byb = slot >> 2;                // 0..127
    const int by = xcd * BANDY + byb;         // 0..1023

    const int c = (bx * BLOCK + threadIdx.x) * CPT;
    const int rbase = by * RPT;
    const int lane = threadIdx.x & 63;
    const bool isL = (lane == 0);
    const bool isR = (lane == 63);

    // Issue all 6 vector row loads up front (max MLP).
    vfloat4 v[NROWS];
#pragma unroll
    for (int i = 0; i < NROWS; ++i) {
        const int rr = rbase - 1 + i;
        if (rr >= 0 && rr < H)
            v[i] = *(const vfloat4*)(x + (size_t)rr * W + c);
        else
            v[i] = (vfloat4)(0.f);
    }

    // Wave-edge halo patches: lane 0 needs col c-1, lane 63 needs col c+4;
    // all other lanes get halos from neighbor lanes via shuffles below.
    float edge[NROWS];
#pragma unroll
    for (int i = 0; i < NROWS; ++i) edge[i] = 0.f;
    if (isL) {
#pragma unroll
        for (int i = 0; i < NROWS; ++i) {
            const int rr = rbase - 1 + i;
            if (rr >= 0 && rr < H && c > 0)
                edge[i] = x[(size_t)rr * W + c - 1];
        }
    } else if (isR) {
#pragma unroll
        for (int i = 0; i < NROWS; ++i) {
            const int rr = rbase - 1 + i;
            if (rr >= 0 && rr < H && c + CPT < W)
                edge[i] = x[(size_t)rr * W + c + CPT];
        }
    }

    // Uniform loads -> SGPRs.
    float wv[9];
#pragma unroll
    for (int i = 0; i < 9; ++i) wv[i] = w9[i];
    const float b = bias[0];

    vfloat4 acc[RPT];
#pragma unroll
    for (int j = 0; j < RPT; ++j) acc[j] = (vfloat4)(b);

    // Row-streaming accumulation: input row i contributes to outputs
    // j = i-2..i (tap dr = i-j). Per-output order is rows j, j+1, j+2 —
    // identical to the previous j-major loop, so numerics are unchanged.
#pragma unroll
    for (int i = 0; i < NROWS; ++i) {
        float lfv = __shfl_up(v[i].w, 1);
        float rtv = __shfl_down(v[i].x, 1);
        lfv = isL ? edge[i] : lfv;
        rtv = isR ? edge[i] : rtv;
#pragma unroll
        for (int dr = 0; dr < 3; ++dr) {
            const int j = i - dr;
            if (j >= 0 && j < RPT) {
                const float w0 = wv[dr * 3 + 0];
                const float w1 = wv[dr * 3 + 1];
                const float w2 = wv[dr * 3 + 2];
                acc[j].x = fmaf(w0, lfv,    fmaf(w1, v[i].x, fmaf(w2, v[i].y, acc[j].x)));
                acc[j].y = fmaf(w0, v[i].x, fmaf(w1, v[i].y, fmaf(w2, v[i].z, acc[j].y)));
                acc[j].z = fmaf(w0, v[i].y, fmaf(w1, v[i].z, fmaf(w2, v[i].w, acc[j].z)));
                acc[j].w = fmaf(w0, v[i].z, fmaf(w1, v[i].w, fmaf(w2, rtv,    acc[j].w)));
            }
        }
    }

#pragma unroll
    for (int j = 0; j < RPT; ++j) {
        __builtin_nontemporal_store(acc[j],
            (vfloat4*)(out + (size_t)(rbase + j) * W + c));
    }
}

extern "C" void kernel_launch(void* const* d_in, const int* in_sizes, int n_in,
                              void* d_out, int out_size, void* d_ws, size_t ws_size,
                              hipStream_t stream) {
    const float* x = (const float*)d_in[0];
    const float* w = (const float*)d_in[1];
    const float* bias = (const float*)d_in[2];
    float* out = (float*)d_out;

    dim3 block(BLOCK, 1, 1);
    dim3 grid(NBX * NBY, 1, 1);   // 4096 blocks, XCD-banded remap in-kernel
    conv3x3_stripe<<<grid, block, 0, stream>>>(x, w, bias, out);
}